// Round 5
// baseline (419.091 us; speedup 1.0000x reference)
//
#include <hip/hip_runtime.h>
#include <math.h>

#define EMB_D 64
#define N_EMB_K 1024
#define HW 4096        // 64*64
#define CHW 262144     // 64*4096
#define NPTS 65536     // 16*64*64
#define Q_OFF 1
#define PERP_OFF 4194305
#define ENC_OFF 4194306
#define FRAG_OFF 4096   // floats: W fragments at ws+16KB
#define IDX_OFF 69632   // floats: idx array (if ws large enough)

// ws layout (floats): [0..1023] c[k] ; [1024..2047] hist(uint) ; [2048] loss ;
// [4096..69631] hi/lo bf16 B-frags (256 KB) ; [69632..135167] idx (optional)

typedef __attribute__((ext_vector_type(8))) short short8;   // MFMA A/B frag
typedef __attribute__((ext_vector_type(4))) float float4v;  // MFMA C/D frag
typedef __attribute__((ext_vector_type(2))) float f2;
typedef __attribute__((ext_vector_type(4))) float f4;

union S8 { short8 v; unsigned short u[8]; };

__device__ __forceinline__ unsigned short f2bf_rne(float f) {
    unsigned u = __builtin_bit_cast(unsigned, f);
    unsigned r = u + 0x7FFFu + ((u >> 16) & 1u);
    return (unsigned short)(r >> 16);
}
__device__ __forceinline__ float bf2f(unsigned short h) {
    unsigned u = ((unsigned)h) << 16;
    return __builtin_bit_cast(float, u);
}

__global__ __launch_bounds__(256) void vq_prep(const float* __restrict__ W,
                                               float* __restrict__ ws) {
    const int gid = blockIdx.x * 256 + threadIdx.x;   // 0..8191
    {
        const int code = gid >> 3;
        const int seg  = gid & 7;
        const int d0   = seg << 3;
        const int t    = code >> 4;
        const int n    = code & 15;
        const int ks   = seg >> 2;
        const int lane = ((seg & 3) << 4) + n;
        const float4* wp = (const float4*)(W + (code << 6) + d0);
        const float4 g0 = wp[0], g1 = wp[1];
        const float vv[8] = {g0.x, g0.y, g0.z, g0.w, g1.x, g1.y, g1.z, g1.w};
        S8 hs, ls;
        #pragma unroll
        for (int j = 0; j < 8; ++j) {
            hs.u[j] = f2bf_rne(vv[j]);
            ls.u[j] = f2bf_rne(vv[j] - bf2f(hs.u[j]));
        }
        short8* frag = (short8*)(ws + FRAG_OFF);
        frag[(t * 4 + ks * 2 + 0) * 64 + lane] = hs.v;
        frag[(t * 4 + ks * 2 + 1) * 64 + lane] = ls.v;
    }
    if (gid < N_EMB_K) {
        const float* wk = W + (gid << 6);
        float s = 0.f;
        #pragma unroll
        for (int d = 0; d < EMB_D; ++d) s = fmaf(wk[d], wk[d], s);
        ws[gid] = 0.5f * s;
        ((unsigned int*)ws)[1024 + gid] = 0u;
        if (gid == 0) ws[2048] = 0.f;
    }
}

__global__ __launch_bounds__(256, 4) void vq_argmin(const float* __restrict__ in,
                                                    const float* __restrict__ W,
                                                    float* __restrict__ out,
                                                    float* __restrict__ ws,
                                                    int* __restrict__ idxbuf,
                                                    int idxstride) {
    __shared__ float x_lds[64 * 64];   // [d][p] fp32, 16 KB
    __shared__ int   s_bk[64];

    const int tid  = threadIdx.x;
    const int lane = tid & 63;
    const int wv   = tid >> 6;
    const int n16  = lane & 15;
    const int quad = lane >> 4;

    const int blk = blockIdx.x;
    const int b   = blk >> 6;
    const int hw0 = (blk & 63) * 64;

    {
        const float* src = in + (size_t)b * CHW + hw0;
        #pragma unroll
        for (int i = 0; i < 16; ++i) {
            const int d = wv * 16 + i;
            x_lds[d * 64 + lane] = src[d * HW + lane];
        }
    }
    __syncthreads();

    // A frags (hi/lo): m = lane&15, k = quad*8 + j
    short8 ah0, al0, ah1, al1;
    {
        const int p = wv * 16 + n16;
        S8 h0, l0, h1, l1;
        #pragma unroll
        for (int j = 0; j < 8; ++j) {
            const float v0 = x_lds[(quad * 8 + j) * 64 + p];
            const float v1 = x_lds[(32 + quad * 8 + j) * 64 + p];
            h0.u[j] = f2bf_rne(v0);
            l0.u[j] = f2bf_rne(v0 - bf2f(h0.u[j]));
            h1.u[j] = f2bf_rne(v1);
            l1.u[j] = f2bf_rne(v1 - bf2f(h1.u[j]));
        }
        ah0 = h0.v; al0 = l0.v; ah1 = h1.v; al1 = l1.v;
    }

    float bestv[4] = {-3.0e38f, -3.0e38f, -3.0e38f, -3.0e38f};
    int   bestk[4] = {0, 0, 0, 0};
    const float*  cvec = ws;
    const short8* frag = (const short8*)(ws + FRAG_OFF);

    // barrier-free, store-free k-loop: 4 b128 loads + 6 MFMAs per 16-code tile
    #pragma unroll 4
    for (int t = 0; t < 64; ++t) {
        const int cb = (t << 2) * 64 + lane;
        const short8 bh0 = frag[cb];
        const short8 bl0 = frag[cb + 64];
        const short8 bh1 = frag[cb + 128];
        const short8 bl1 = frag[cb + 192];
        const float  cv  = cvec[(t << 4) + n16];
        float4v acc = {-cv, -cv, -cv, -cv};    // score = x.w - 0.5||w||^2
        acc = __builtin_amdgcn_mfma_f32_16x16x32_bf16(ah0, bh0, acc, 0, 0, 0);
        acc = __builtin_amdgcn_mfma_f32_16x16x32_bf16(ah1, bh1, acc, 0, 0, 0);
        acc = __builtin_amdgcn_mfma_f32_16x16x32_bf16(al0, bh0, acc, 0, 0, 0);
        acc = __builtin_amdgcn_mfma_f32_16x16x32_bf16(al1, bh1, acc, 0, 0, 0);
        acc = __builtin_amdgcn_mfma_f32_16x16x32_bf16(ah0, bl0, acc, 0, 0, 0);
        acc = __builtin_amdgcn_mfma_f32_16x16x32_bf16(ah1, bl1, acc, 0, 0, 0);
        const int code = (t << 4) + n16;
        #pragma unroll
        for (int r = 0; r < 4; ++r) {
            if (acc[r] > bestv[r]) { bestv[r] = acc[r]; bestk[r] = code; }
        }
    }

    #pragma unroll
    for (int off = 1; off < 16; off <<= 1) {
        #pragma unroll
        for (int r = 0; r < 4; ++r) {
            const float ov = __shfl_xor(bestv[r], off, 64);
            const int   oi = __shfl_xor(bestk[r], off, 64);
            if (ov > bestv[r] || (ov == bestv[r] && oi < bestk[r])) {
                bestv[r] = ov; bestk[r] = oi;
            }
        }
    }
    if (n16 == 0) {
        #pragma unroll
        for (int r = 0; r < 4; ++r) s_bk[wv * 16 + quad * 4 + r] = bestk[r];
    }
    __syncthreads();

    if (tid < 64) {
        const int bk = s_bk[tid];
        atomicAdd((unsigned int*)ws + 1024 + bk, 1u);
        idxbuf[(size_t)(blk * 64 + tid) * idxstride] = bk;
    }

    // quantized_st (NCHW) + exact fp32 loss
    {
        float* quant = out + Q_OFF;
        const int p  = lane;
        const int bk = s_bk[p];
        const float* wrow = W + (bk << 6);
        float lsum = 0.f;
        #pragma unroll
        for (int dd = 0; dd < 16; ++dd) {
            const int d = wv * 16 + dd;
            const float xv  = x_lds[d * 64 + p];
            const float qv  = wrow[d];
            const float diff = qv - xv;
            lsum = fmaf(diff, diff, lsum);
            __builtin_nontemporal_store(xv + diff,
                quant + (size_t)b * CHW + d * HW + hw0 + p);
        }
        #pragma unroll
        for (int off = 1; off < 64; off <<= 1) lsum += __shfl_xor(lsum, off, 64);
        if (lane == 0) atomicAdd(ws + 2048, lsum);
    }
}

// pure streaming one-hot writer: 64 rows/block, aligned float4 nontemporal stores
__global__ __launch_bounds__(256, 4) void vq_enc(float* __restrict__ out,
                                                 const int* __restrict__ idxbuf,
                                                 int idxstride) {
    __shared__ int s_idx[64];
    const int tid = threadIdx.x;
    const int blk = blockIdx.x;
    if (tid < 64) s_idx[tid] = idxbuf[(size_t)(blk * 64 + tid) * idxstride];
    __syncthreads();

    float* encbase = out + ENC_OFF;   // byte addr = 8 mod 16; +2 floats -> 16B aligned
    for (int r = 0; r < 64; ++r) {
        const int bk = s_idx[r];
        float* row = encbase + ((size_t)(blk * 64 + r) << 10);
        if (tid < 255) {
            const int c = 2 + 4 * tid;
            f4 v;
            v.x = (bk == c)     ? 1.0f : 0.0f;
            v.y = (bk == c + 1) ? 1.0f : 0.0f;
            v.z = (bk == c + 2) ? 1.0f : 0.0f;
            v.w = (bk == c + 3) ? 1.0f : 0.0f;
            __builtin_nontemporal_store(v, (f4*)(row + c));
        } else {
            f2 v0, v1;
            v0.x = (bk == 0)    ? 1.0f : 0.0f;
            v0.y = (bk == 1)    ? 1.0f : 0.0f;
            v1.x = (bk == 1022) ? 1.0f : 0.0f;
            v1.y = (bk == 1023) ? 1.0f : 0.0f;
            __builtin_nontemporal_store(v0, (f2*)(row));
            __builtin_nontemporal_store(v1, (f2*)(row + 1022));
        }
    }
}

__global__ __launch_bounds__(256) void vq_final(const float* __restrict__ ws,
                                                float* __restrict__ out) {
    __shared__ float red[256];
    const int tid = threadIdx.x;
    const unsigned int* hist = (const unsigned int*)ws + 1024;
    float local = 0.f;
    #pragma unroll
    for (int j = 0; j < 4; ++j) {
        const unsigned int cnt = hist[tid + j * 256];
        const float pr = (float)cnt * (1.0f / 65536.0f);
        local += pr * logf(pr + 1e-10f);
    }
    red[tid] = local;
    __syncthreads();
    for (int off = 128; off > 0; off >>= 1) {
        if (tid < off) red[tid] += red[tid + off];
        __syncthreads();
    }
    if (tid == 0) {
        out[PERP_OFF] = expf(-red[0]);
        out[0] = 1.25f * ws[2048] * (1.0f / 4194304.0f);
    }
}

extern "C" void kernel_launch(void* const* d_in, const int* in_sizes, int n_in,
                              void* d_out, int out_size, void* d_ws, size_t ws_size,
                              hipStream_t stream) {
    const float* in = (const float*)d_in[0];   // (16,64,64,64) fp32 NCHW
    const float* W  = (const float*)d_in[1];   // (1024,64) fp32
    float* out = (float*)d_out;                // [loss | quant(4194304) | perp | enc(67108864)]
    float* ws  = (float*)d_ws;

    // idx handoff: ws tail if it fits, else parked in enc col-0 (overwritten by vq_enc)
    int* idxbuf;
    int  idxstride;
    if (ws_size >= (size_t)(IDX_OFF + NPTS) * 4) {
        idxbuf = (int*)ws + IDX_OFF;
        idxstride = 1;
    } else {
        idxbuf = (int*)(out + ENC_OFF);
        idxstride = 1024;
    }

    vq_prep<<<32, 256, 0, stream>>>(W, ws);
    vq_argmin<<<NPTS / 64, 256, 0, stream>>>(in, W, out, ws, idxbuf, idxstride);
    vq_enc<<<NPTS / 64, 256, 0, stream>>>(out, idxbuf, idxstride);
    vq_final<<<1, 256, 0, stream>>>(ws, out);
}

// Round 6
// 380.373 us; speedup vs baseline: 1.1018x; 1.1018x over previous
//
#include <hip/hip_runtime.h>
#include <math.h>

#define EMB_D 64
#define N_EMB_K 1024
#define HW 4096        // 64*64
#define CHW 262144     // 64*4096
#define NPTS 65536     // 16*64*64
#define Q_OFF 1
#define PERP_OFF 4194305
#define ENC_OFF 4194306
#define FRAG_OFF 4096   // floats: W fragments at ws+16KB

// ws layout (floats): [0..1023] c[k]=0.5||W_k||^2 ; [1024..2047] hist(uint) ;
// [2048] loss ; [4096..69631] hi/lo bf16 B-frags (256 KB)

typedef __attribute__((ext_vector_type(8))) short short8;   // MFMA A/B frag
typedef __attribute__((ext_vector_type(4))) float float4v;  // MFMA C/D frag
typedef __attribute__((ext_vector_type(2))) float f2;
typedef __attribute__((ext_vector_type(4))) float f4;

union S8 { short8 v; unsigned short u[8]; };

__device__ __forceinline__ unsigned short f2bf_rne(float f) {
    unsigned u = __builtin_bit_cast(unsigned, f);
    unsigned r = u + 0x7FFFu + ((u >> 16) & 1u);
    return (unsigned short)(r >> 16);
}
__device__ __forceinline__ float bf2f(unsigned short h) {
    unsigned u = ((unsigned)h) << 16;
    return __builtin_bit_cast(float, u);
}

__global__ __launch_bounds__(256) void vq_prep(const float* __restrict__ W,
                                               float* __restrict__ ws) {
    const int gid = blockIdx.x * 256 + threadIdx.x;   // 0..8191
    {
        const int code = gid >> 3;
        const int seg  = gid & 7;
        const int d0   = seg << 3;
        const int t    = code >> 4;
        const int n    = code & 15;
        const int ks   = seg >> 2;
        const int lane = ((seg & 3) << 4) + n;
        const float4* wp = (const float4*)(W + (code << 6) + d0);
        const float4 g0 = wp[0], g1 = wp[1];
        const float vv[8] = {g0.x, g0.y, g0.z, g0.w, g1.x, g1.y, g1.z, g1.w};
        S8 hs, ls;
        #pragma unroll
        for (int j = 0; j < 8; ++j) {
            hs.u[j] = f2bf_rne(vv[j]);
            ls.u[j] = f2bf_rne(vv[j] - bf2f(hs.u[j]));
        }
        short8* frag = (short8*)(ws + FRAG_OFF);
        frag[(t * 4 + ks * 2 + 0) * 64 + lane] = hs.v;
        frag[(t * 4 + ks * 2 + 1) * 64 + lane] = ls.v;
    }
    if (gid < N_EMB_K) {
        const float* wk = W + (gid << 6);
        float s = 0.f;
        #pragma unroll
        for (int d = 0; d < EMB_D; ++d) s = fmaf(wk[d], wk[d], s);
        ws[gid] = 0.5f * s;
        ((unsigned int*)ws)[1024 + gid] = 0u;
        if (gid == 0) ws[2048] = 0.f;
    }
}

// 512 blocks x 256 thr; block owns 128 points; wave owns 32 points (2 A-tiles)
__global__ __launch_bounds__(256, 2) void vq_main(const float* __restrict__ in,
                                                  const float* __restrict__ W,
                                                  float* __restrict__ out,
                                                  float* __restrict__ ws) {
    __shared__ float x_lds[64 * 128];   // [d][p], 32 KB
    __shared__ int   s_bk[128];

    const int tid  = threadIdx.x;
    const int lane = tid & 63;
    const int wv   = tid >> 6;
    const int n16  = lane & 15;
    const int quad = lane >> 4;

    const int blk = blockIdx.x;
    const int b   = blk >> 5;              // image (32 blocks per image)
    const int hw0 = (blk & 31) * 128;      // 128 consecutive hw positions

    // ---- stage x tile (64 d x 128 p), coalesced ----
    {
        const float* src = in + (size_t)b * CHW + hw0;
        #pragma unroll
        for (int i = 0; i < 32; ++i) {
            const int idx = i * 256 + tid;       // 0..8191
            const int d = idx >> 7, p = idx & 127;
            x_lds[idx] = src[d * HW + p];
        }
    }
    __syncthreads();

    // ---- A frags (hi/lo), two 16-pt tiles per wave: m=lane&15, k=quad*8+j ----
    short8 a0h0, a0l0, a0h1, a0l1, a1h0, a1l0, a1h1, a1l1;
    {
        const int p0 = wv * 32 + n16;
        const int p1 = p0 + 16;
        S8 t0h0, t0l0, t0h1, t0l1, t1h0, t1l0, t1h1, t1l1;
        #pragma unroll
        for (int j = 0; j < 8; ++j) {
            const int d = quad * 8 + j;
            const float v00 = x_lds[d * 128 + p0];
            const float v01 = x_lds[(d + 32) * 128 + p0];
            const float v10 = x_lds[d * 128 + p1];
            const float v11 = x_lds[(d + 32) * 128 + p1];
            t0h0.u[j] = f2bf_rne(v00); t0l0.u[j] = f2bf_rne(v00 - bf2f(t0h0.u[j]));
            t0h1.u[j] = f2bf_rne(v01); t0l1.u[j] = f2bf_rne(v01 - bf2f(t0h1.u[j]));
            t1h0.u[j] = f2bf_rne(v10); t1l0.u[j] = f2bf_rne(v10 - bf2f(t1h0.u[j]));
            t1h1.u[j] = f2bf_rne(v11); t1l1.u[j] = f2bf_rne(v11 - bf2f(t1h1.u[j]));
        }
        a0h0 = t0h0.v; a0l0 = t0l0.v; a0h1 = t0h1.v; a0l1 = t0l1.v;
        a1h0 = t1h0.v; a1l0 = t1l0.v; a1h1 = t1h1.v; a1l1 = t1l1.v;
    }

    float bv0[4] = {-3.0e38f, -3.0e38f, -3.0e38f, -3.0e38f};
    float bv1[4] = {-3.0e38f, -3.0e38f, -3.0e38f, -3.0e38f};
    int   bk0[4] = {0, 0, 0, 0};
    int   bk1[4] = {0, 0, 0, 0};
    const float*  cvec = ws;
    const short8* frag = (const short8*)(ws + FRAG_OFF);

    // ---- barrier-free, store-free k-loop: 4 b128 loads serve 12 MFMAs ----
    #pragma unroll 2
    for (int t = 0; t < 64; ++t) {
        const int cb = (t << 2) * 64 + lane;
        const short8 bh0 = frag[cb];
        const short8 bl0 = frag[cb + 64];
        const short8 bh1 = frag[cb + 128];
        const short8 bl1 = frag[cb + 192];
        const float  cv  = cvec[(t << 4) + n16];
        float4v acc0 = {-cv, -cv, -cv, -cv};   // score = x.w - 0.5||w||^2
        float4v acc1 = {-cv, -cv, -cv, -cv};
        acc0 = __builtin_amdgcn_mfma_f32_16x16x32_bf16(a0h0, bh0, acc0, 0, 0, 0);
        acc1 = __builtin_amdgcn_mfma_f32_16x16x32_bf16(a1h0, bh0, acc1, 0, 0, 0);
        acc0 = __builtin_amdgcn_mfma_f32_16x16x32_bf16(a0h1, bh1, acc0, 0, 0, 0);
        acc1 = __builtin_amdgcn_mfma_f32_16x16x32_bf16(a1h1, bh1, acc1, 0, 0, 0);
        acc0 = __builtin_amdgcn_mfma_f32_16x16x32_bf16(a0l0, bh0, acc0, 0, 0, 0);
        acc1 = __builtin_amdgcn_mfma_f32_16x16x32_bf16(a1l0, bh0, acc1, 0, 0, 0);
        acc0 = __builtin_amdgcn_mfma_f32_16x16x32_bf16(a0l1, bh1, acc0, 0, 0, 0);
        acc1 = __builtin_amdgcn_mfma_f32_16x16x32_bf16(a1l1, bh1, acc1, 0, 0, 0);
        acc0 = __builtin_amdgcn_mfma_f32_16x16x32_bf16(a0h0, bl0, acc0, 0, 0, 0);
        acc1 = __builtin_amdgcn_mfma_f32_16x16x32_bf16(a1h0, bl0, acc1, 0, 0, 0);
        acc0 = __builtin_amdgcn_mfma_f32_16x16x32_bf16(a0h1, bl1, acc0, 0, 0, 0);
        acc1 = __builtin_amdgcn_mfma_f32_16x16x32_bf16(a1h1, bl1, acc1, 0, 0, 0);
        const int code = (t << 4) + n16;
        #pragma unroll
        for (int r = 0; r < 4; ++r) {
            if (acc0[r] > bv0[r]) { bv0[r] = acc0[r]; bk0[r] = code; }  // strict > => lowest k
            if (acc1[r] > bv1[r]) { bv1[r] = acc1[r]; bk1[r] = code; }
        }
    }

    // ---- reduce across the 16 code-lanes of each row group ----
    #pragma unroll
    for (int off = 1; off < 16; off <<= 1) {
        #pragma unroll
        for (int r = 0; r < 4; ++r) {
            float ov = __shfl_xor(bv0[r], off, 64);
            int   oi = __shfl_xor(bk0[r], off, 64);
            if (ov > bv0[r] || (ov == bv0[r] && oi < bk0[r])) { bv0[r] = ov; bk0[r] = oi; }
            ov = __shfl_xor(bv1[r], off, 64);
            oi = __shfl_xor(bk1[r], off, 64);
            if (ov > bv1[r] || (ov == bv1[r] && oi < bk1[r])) { bv1[r] = ov; bk1[r] = oi; }
        }
    }
    if (n16 == 0) {
        #pragma unroll
        for (int r = 0; r < 4; ++r) {
            s_bk[wv * 32 + quad * 4 + r]      = bk0[r];
            s_bk[wv * 32 + 16 + quad * 4 + r] = bk1[r];
        }
    }
    __syncthreads();

    if (tid < 128) atomicAdd((unsigned int*)ws + 1024 + s_bk[tid], 1u);

    // ---- encodings epilogue: 128 rows, aligned f4 NT stores ----
    {
        float* encbase = out + ENC_OFF;   // byte ≡ 8 mod 16; +2 floats → 16B aligned
        for (int r = 0; r < 128; ++r) {
            const int bk = s_bk[r];
            float* row = encbase + ((size_t)(blk * 128 + r) << 10);
            if (tid < 255) {
                const int c = 2 + 4 * tid;
                f4 v;
                v.x = (bk == c)     ? 1.0f : 0.0f;
                v.y = (bk == c + 1) ? 1.0f : 0.0f;
                v.z = (bk == c + 2) ? 1.0f : 0.0f;
                v.w = (bk == c + 3) ? 1.0f : 0.0f;
                __builtin_nontemporal_store(v, (f4*)(row + c));
            } else {
                f2 v0, v1;
                v0.x = (bk == 0)    ? 1.0f : 0.0f;
                v0.y = (bk == 1)    ? 1.0f : 0.0f;
                v1.x = (bk == 1022) ? 1.0f : 0.0f;
                v1.y = (bk == 1023) ? 1.0f : 0.0f;
                __builtin_nontemporal_store(v0, (f2*)(row));
                __builtin_nontemporal_store(v1, (f2*)(row + 1022));
            }
        }
    }

    // ---- quantized_st (NCHW) + exact fp32 loss ----
    {
        float* quant = out + Q_OFF;
        const int p    = tid & 127;        // wave-contiguous p
        const int half = tid >> 7;
        const int bk = s_bk[p];
        const float* wrow = W + (bk << 6);
        float lsum = 0.f;
        #pragma unroll
        for (int dd = 0; dd < 32; ++dd) {
            const int d = half * 32 + dd;
            const float xv  = x_lds[d * 128 + p];
            const float qv  = wrow[d];
            const float diff = qv - xv;
            lsum = fmaf(diff, diff, lsum);
            __builtin_nontemporal_store(xv + diff,
                quant + (size_t)b * CHW + d * HW + hw0 + p);
        }
        #pragma unroll
        for (int off = 1; off < 64; off <<= 1) lsum += __shfl_xor(lsum, off, 64);
        if (lane == 0) atomicAdd(ws + 2048, lsum);
    }
}

__global__ __launch_bounds__(256) void vq_final(const float* __restrict__ ws,
                                                float* __restrict__ out) {
    __shared__ float red[256];
    const int tid = threadIdx.x;
    const unsigned int* hist = (const unsigned int*)ws + 1024;
    float local = 0.f;
    #pragma unroll
    for (int j = 0; j < 4; ++j) {
        const unsigned int cnt = hist[tid + j * 256];
        const float pr = (float)cnt * (1.0f / 65536.0f);
        local += pr * logf(pr + 1e-10f);
    }
    red[tid] = local;
    __syncthreads();
    for (int off = 128; off > 0; off >>= 1) {
        if (tid < off) red[tid] += red[tid + off];
        __syncthreads();
    }
    if (tid == 0) {
        out[PERP_OFF] = expf(-red[0]);
        out[0] = 1.25f * ws[2048] * (1.0f / 4194304.0f);
    }
}

extern "C" void kernel_launch(void* const* d_in, const int* in_sizes, int n_in,
                              void* d_out, int out_size, void* d_ws, size_t ws_size,
                              hipStream_t stream) {
    const float* in = (const float*)d_in[0];   // (16,64,64,64) fp32 NCHW
    const float* W  = (const float*)d_in[1];   // (1024,64) fp32
    float* out = (float*)d_out;                // [loss | quant(4194304) | perp | enc(67108864)]
    float* ws  = (float*)d_ws;

    vq_prep<<<32, 256, 0, stream>>>(W, ws);
    vq_main<<<NPTS / 128, 256, 0, stream>>>(in, W, out, ws);
    vq_final<<<1, 256, 0, stream>>>(ws, out);
}

// Round 7
// 368.551 us; speedup vs baseline: 1.1371x; 1.0321x over previous
//
#include <hip/hip_runtime.h>
#include <math.h>

#define EMB_D 64
#define N_EMB_K 1024
#define HW 4096        // 64*64
#define CHW 262144     // 64*4096
#define NPTS 65536     // 16*64*64
#define Q_OFF 1
#define PERP_OFF 4194305
#define ENC_OFF 4194306
#define FRAG_OFF 4096   // floats: W fragments at ws+16KB

// ws layout (floats): [0..1023] c[k]=0.5||W_k||^2 ; [1024..2047] hist(uint) ;
// [2048] loss ; [4096..69631] hi/lo bf16 B-frags (256 KB)

typedef __attribute__((ext_vector_type(8))) short short8;   // MFMA A/B frag
typedef __attribute__((ext_vector_type(4))) float float4v;  // MFMA C/D frag
typedef __attribute__((ext_vector_type(2))) float f2;
typedef __attribute__((ext_vector_type(4))) float f4;

union S8 { short8 v; unsigned short u[8]; };

__device__ __forceinline__ unsigned short f2bf_rne(float f) {
    unsigned u = __builtin_bit_cast(unsigned, f);
    unsigned r = u + 0x7FFFu + ((u >> 16) & 1u);
    return (unsigned short)(r >> 16);
}
__device__ __forceinline__ float bf2f(unsigned short h) {
    unsigned u = ((unsigned)h) << 16;
    return __builtin_bit_cast(float, u);
}

__global__ __launch_bounds__(256) void vq_prep(const float* __restrict__ W,
                                               float* __restrict__ ws) {
    const int gid = blockIdx.x * 256 + threadIdx.x;   // 0..8191
    {
        const int code = gid >> 3;
        const int seg  = gid & 7;
        const int d0   = seg << 3;
        const int t    = code >> 4;
        const int n    = code & 15;
        const int ks   = seg >> 2;
        const int lane = ((seg & 3) << 4) + n;
        const float4* wp = (const float4*)(W + (code << 6) + d0);
        const float4 g0 = wp[0], g1 = wp[1];
        const float vv[8] = {g0.x, g0.y, g0.z, g0.w, g1.x, g1.y, g1.z, g1.w};
        S8 hs, ls;
        #pragma unroll
        for (int j = 0; j < 8; ++j) {
            hs.u[j] = f2bf_rne(vv[j]);
            ls.u[j] = f2bf_rne(vv[j] - bf2f(hs.u[j]));
        }
        short8* frag = (short8*)(ws + FRAG_OFF);
        frag[(t * 4 + ks * 2 + 0) * 64 + lane] = hs.v;
        frag[(t * 4 + ks * 2 + 1) * 64 + lane] = ls.v;
    }
    if (gid < N_EMB_K) {
        const float* wk = W + (gid << 6);
        float s = 0.f;
        #pragma unroll
        for (int d = 0; d < EMB_D; ++d) s = fmaf(wk[d], wk[d], s);
        ws[gid] = 0.5f * s;
        ((unsigned int*)ws)[1024 + gid] = 0u;
        if (gid == 0) ws[2048] = 0.f;
    }
}

// 512 blocks x 256 thr; block owns 128 points; wave owns 32 points (2 A-tiles)
__global__ __launch_bounds__(256, 2) void vq_main(const float* __restrict__ in,
                                                  const float* __restrict__ W,
                                                  float* __restrict__ out,
                                                  float* __restrict__ ws) {
    __shared__ float x_lds[64 * 128];   // [d][p], 32 KB
    __shared__ int   s_bk[128];

    const int tid  = threadIdx.x;
    const int lane = tid & 63;
    const int wv   = tid >> 6;
    const int n16  = lane & 15;
    const int quad = lane >> 4;

    const int blk = blockIdx.x;
    const int b   = blk >> 5;              // image (32 blocks per image)
    const int hw0 = (blk & 31) * 128;      // 128 consecutive hw positions

    // ---- stage x tile (64 d x 128 p), coalesced ----
    {
        const float* src = in + (size_t)b * CHW + hw0;
        #pragma unroll
        for (int i = 0; i < 32; ++i) {
            const int idx = i * 256 + tid;       // 0..8191
            const int d = idx >> 7, p = idx & 127;
            x_lds[idx] = src[d * HW + p];
        }
    }
    __syncthreads();

    // ---- A frags (hi/lo), two 16-pt tiles per wave: m=lane&15, k=quad*8+j ----
    short8 a0h0, a0l0, a0h1, a0l1, a1h0, a1l0, a1h1, a1l1;
    {
        const int p0 = wv * 32 + n16;
        const int p1 = p0 + 16;
        S8 t0h0, t0l0, t0h1, t0l1, t1h0, t1l0, t1h1, t1l1;
        #pragma unroll
        for (int j = 0; j < 8; ++j) {
            const int d = quad * 8 + j;
            const float v00 = x_lds[d * 128 + p0];
            const float v01 = x_lds[(d + 32) * 128 + p0];
            const float v10 = x_lds[d * 128 + p1];
            const float v11 = x_lds[(d + 32) * 128 + p1];
            t0h0.u[j] = f2bf_rne(v00); t0l0.u[j] = f2bf_rne(v00 - bf2f(t0h0.u[j]));
            t0h1.u[j] = f2bf_rne(v01); t0l1.u[j] = f2bf_rne(v01 - bf2f(t0h1.u[j]));
            t1h0.u[j] = f2bf_rne(v10); t1l0.u[j] = f2bf_rne(v10 - bf2f(t1h0.u[j]));
            t1h1.u[j] = f2bf_rne(v11); t1l1.u[j] = f2bf_rne(v11 - bf2f(t1h1.u[j]));
        }
        a0h0 = t0h0.v; a0l0 = t0l0.v; a0h1 = t0h1.v; a0l1 = t0l1.v;
        a1h0 = t1h0.v; a1l0 = t1l0.v; a1h1 = t1h1.v; a1l1 = t1l1.v;
    }

    float bv0[4] = {-3.0e38f, -3.0e38f, -3.0e38f, -3.0e38f};
    float bv1[4] = {-3.0e38f, -3.0e38f, -3.0e38f, -3.0e38f};
    int   bk0[4] = {0, 0, 0, 0};
    int   bk1[4] = {0, 0, 0, 0};
    const float*  cvec = ws;
    const short8* frag = (const short8*)(ws + FRAG_OFF);

    // ---- barrier-free, store-free k-loop: 4 b128 loads serve 12 MFMAs ----
    #pragma unroll 2
    for (int t = 0; t < 64; ++t) {
        const int cb = (t << 2) * 64 + lane;
        const short8 bh0 = frag[cb];
        const short8 bl0 = frag[cb + 64];
        const short8 bh1 = frag[cb + 128];
        const short8 bl1 = frag[cb + 192];
        const float  cv  = cvec[(t << 4) + n16];
        float4v acc0 = {-cv, -cv, -cv, -cv};   // score = x.w - 0.5||w||^2
        float4v acc1 = {-cv, -cv, -cv, -cv};
        acc0 = __builtin_amdgcn_mfma_f32_16x16x32_bf16(a0h0, bh0, acc0, 0, 0, 0);
        acc1 = __builtin_amdgcn_mfma_f32_16x16x32_bf16(a1h0, bh0, acc1, 0, 0, 0);
        acc0 = __builtin_amdgcn_mfma_f32_16x16x32_bf16(a0h1, bh1, acc0, 0, 0, 0);
        acc1 = __builtin_amdgcn_mfma_f32_16x16x32_bf16(a1h1, bh1, acc1, 0, 0, 0);
        acc0 = __builtin_amdgcn_mfma_f32_16x16x32_bf16(a0l0, bh0, acc0, 0, 0, 0);
        acc1 = __builtin_amdgcn_mfma_f32_16x16x32_bf16(a1l0, bh0, acc1, 0, 0, 0);
        acc0 = __builtin_amdgcn_mfma_f32_16x16x32_bf16(a0l1, bh1, acc0, 0, 0, 0);
        acc1 = __builtin_amdgcn_mfma_f32_16x16x32_bf16(a1l1, bh1, acc1, 0, 0, 0);
        acc0 = __builtin_amdgcn_mfma_f32_16x16x32_bf16(a0h0, bl0, acc0, 0, 0, 0);
        acc1 = __builtin_amdgcn_mfma_f32_16x16x32_bf16(a1h0, bl0, acc1, 0, 0, 0);
        acc0 = __builtin_amdgcn_mfma_f32_16x16x32_bf16(a0h1, bl1, acc0, 0, 0, 0);
        acc1 = __builtin_amdgcn_mfma_f32_16x16x32_bf16(a1h1, bl1, acc1, 0, 0, 0);
        const int code = (t << 4) + n16;
        #pragma unroll
        for (int r = 0; r < 4; ++r) {
            if (acc0[r] > bv0[r]) { bv0[r] = acc0[r]; bk0[r] = code; }  // strict > => lowest k
            if (acc1[r] > bv1[r]) { bv1[r] = acc1[r]; bk1[r] = code; }
        }
    }

    // ---- reduce across the 16 code-lanes of each row group ----
    #pragma unroll
    for (int off = 1; off < 16; off <<= 1) {
        #pragma unroll
        for (int r = 0; r < 4; ++r) {
            float ov = __shfl_xor(bv0[r], off, 64);
            int   oi = __shfl_xor(bk0[r], off, 64);
            if (ov > bv0[r] || (ov == bv0[r] && oi < bk0[r])) { bv0[r] = ov; bk0[r] = oi; }
            ov = __shfl_xor(bv1[r], off, 64);
            oi = __shfl_xor(bk1[r], off, 64);
            if (ov > bv1[r] || (ov == bv1[r] && oi < bk1[r])) { bv1[r] = ov; bk1[r] = oi; }
        }
    }
    if (n16 == 0) {
        #pragma unroll
        for (int r = 0; r < 4; ++r) {
            s_bk[wv * 32 + quad * 4 + r]      = bk0[r];
            s_bk[wv * 32 + 16 + quad * 4 + r] = bk1[r];
        }
    }
    __syncthreads();

    if (tid < 128) atomicAdd((unsigned int*)ws + 1024 + s_bk[tid], 1u);

    // ---- encodings epilogue: 128 rows, aligned f4 PLAIN stores (L2 write-back) ----
    {
        float* encbase = out + ENC_OFF;   // byte ≡ 8 mod 16; +2 floats → 16B aligned
        for (int r = 0; r < 128; ++r) {
            const int bk = s_bk[r];
            float* row = encbase + ((size_t)(blk * 128 + r) << 10);
            if (tid < 255) {
                const int c = 2 + 4 * tid;
                f4 v;
                v.x = (bk == c)     ? 1.0f : 0.0f;
                v.y = (bk == c + 1) ? 1.0f : 0.0f;
                v.z = (bk == c + 2) ? 1.0f : 0.0f;
                v.w = (bk == c + 3) ? 1.0f : 0.0f;
                *(f4*)(row + c) = v;
            } else {
                f2 v0, v1;
                v0.x = (bk == 0)    ? 1.0f : 0.0f;
                v0.y = (bk == 1)    ? 1.0f : 0.0f;
                v1.x = (bk == 1022) ? 1.0f : 0.0f;
                v1.y = (bk == 1023) ? 1.0f : 0.0f;
                *(f2*)(row)        = v0;
                *(f2*)(row + 1022) = v1;
            }
        }
    }

    // ---- quantized_st (NCHW) + exact fp32 loss, plain stores ----
    {
        float* quant = out + Q_OFF;
        const int p    = tid & 127;        // wave-contiguous p
        const int half = tid >> 7;
        const int bk = s_bk[p];
        const float* wrow = W + (bk << 6);
        float lsum = 0.f;
        #pragma unroll
        for (int dd = 0; dd < 32; ++dd) {
            const int d = half * 32 + dd;
            const float xv  = x_lds[d * 128 + p];
            const float qv  = wrow[d];
            const float diff = qv - xv;
            lsum = fmaf(diff, diff, lsum);
            quant[(size_t)b * CHW + d * HW + hw0 + p] = xv + diff;
        }
        #pragma unroll
        for (int off = 1; off < 64; off <<= 1) lsum += __shfl_xor(lsum, off, 64);
        if (lane == 0) atomicAdd(ws + 2048, lsum);
    }
}

__global__ __launch_bounds__(256) void vq_final(const float* __restrict__ ws,
                                                float* __restrict__ out) {
    __shared__ float red[256];
    const int tid = threadIdx.x;
    const unsigned int* hist = (const unsigned int*)ws + 1024;
    float local = 0.f;
    #pragma unroll
    for (int j = 0; j < 4; ++j) {
        const unsigned int cnt = hist[tid + j * 256];
        const float pr = (float)cnt * (1.0f / 65536.0f);
        local += pr * logf(pr + 1e-10f);
    }
    red[tid] = local;
    __syncthreads();
    for (int off = 128; off > 0; off >>= 1) {
        if (tid < off) red[tid] += red[tid + off];
        __syncthreads();
    }
    if (tid == 0) {
        out[PERP_OFF] = expf(-red[0]);
        out[0] = 1.25f * ws[2048] * (1.0f / 4194304.0f);
    }
}

extern "C" void kernel_launch(void* const* d_in, const int* in_sizes, int n_in,
                              void* d_out, int out_size, void* d_ws, size_t ws_size,
                              hipStream_t stream) {
    const float* in = (const float*)d_in[0];   // (16,64,64,64) fp32 NCHW
    const float* W  = (const float*)d_in[1];   // (1024,64) fp32
    float* out = (float*)d_out;                // [loss | quant(4194304) | perp | enc(67108864)]
    float* ws  = (float*)d_ws;

    vq_prep<<<32, 256, 0, stream>>>(W, ws);
    vq_main<<<NPTS / 128, 256, 0, stream>>>(in, W, out, ws);
    vq_final<<<1, 256, 0, stream>>>(ws, out);
}